// Round 3
// baseline (670.761 us; speedup 1.0000x reference)
//
#include <hip/hip_runtime.h>
#include <math.h>

// MoE router: logits[16384,64] = X[16384,2048] @ W^T, top-2, softmax(2).
// Outputs flat: weights [16384*2] f32, then indices [16384*2] as float.
//
// R1: runtime-indexed acc -> scratch spill (293MB writes, 316us).
// R2: acc static but per-lane W global loads = dependent-load latency chain
//     (VALU 27%, 366us). Fix: LDS-tiled GEMM, outer-product register tile.
//
// Structure: 256 blocks x 512 thr. Block = 64 tok x 64 exp.
// 4 teams x 128 thr; team t owns d in [t*512,(t+1)*512), 16 chunks of 32.
// Per thread: 8 tok x 4 exp acc. Per 4d-step: 12 ds_read_b128 / 128 FMA
// -> VALU-bound (256 vs 144 cyc). Double-buffered LDS, 1 barrier/chunk.
// XOR swizzle on 16B cols: all LDS reads <=2-way (free).

#define NTOK 16384
#define DDIM 2048
#define NEXP 64
#define BLK_TOK 64
#define DC 32          // d per chunk
#define NCHUNK 16      // 512 d per team

__global__ __launch_bounds__(512, 2) void moe_gemm_kernel(
    const float* __restrict__ x,      // [NTOK, DDIM]
    const float* __restrict__ gw,     // [NEXP, DDIM]
    float* __restrict__ out)          // weights then indices
{
    // [team][buf][row*8 + col16] ; 64KB each for X and W; lp 16KB -> 144KB
    __shared__ float4 Xl[4][2][BLK_TOK * (DC / 4)];
    __shared__ float4 Wl[4][2][NEXP * (DC / 4)];
    __shared__ float  lp[BLK_TOK * NEXP];

    const int tid  = threadIdx.x;
    const int team = tid >> 7;         // 0..3 (D quarter)
    const int tt   = tid & 127;        // thread within team
    const int tx   = tt & 15;          // expert group: experts tx*4..tx*4+3
    const int ty   = tt >> 4;          // token group:  tokens  ty*8..ty*8+7
    const int tok0 = blockIdx.x * BLK_TOK;
    const int dbase = team * 512;

    // swizzle keys: col' = col ^ ((row>>2)&7)
    const int kw  = tx & 7;            // (exp>>2)&7 for exp = tx*4+n, n<4
    const int kx0 = (2 * ty) & 7;      // (tok>>2)&7 for tok = ty*8+m, m<4
    const int kx1 = (2 * ty + 1) & 7;  // m in 4..7

    float acc[8][4];
#pragma unroll
    for (int m = 0; m < 8; ++m)
#pragma unroll
        for (int n = 0; n < 4; ++n) acc[m][n] = 0.f;

    // ---- staging helpers (unit u = tt + k2*128 -> row u>>3, col16 u&7) ----
#define STAGE_LOAD(nc)                                                        \
    {                                                                         \
        const int dcol = dbase + (nc) * DC;                                   \
        _Pragma("unroll")                                                     \
        for (int k2 = 0; k2 < 4; ++k2) {                                      \
            const int u = tt + k2 * 128;                                      \
            const int r = u >> 3, c = u & 7;                                  \
            gx[k2] = *reinterpret_cast<const float4*>(                        \
                x + (size_t)(tok0 + r) * DDIM + dcol + c * 4);                \
            gv[k2] = *reinterpret_cast<const float4*>(                        \
                gw + (size_t)r * DDIM + dcol + c * 4);                        \
        }                                                                     \
    }
#define STAGE_WRITE(buf)                                                      \
    {                                                                         \
        _Pragma("unroll")                                                     \
        for (int k2 = 0; k2 < 4; ++k2) {                                      \
            const int u = tt + k2 * 128;                                      \
            const int r = u >> 3, c = u & 7;                                  \
            const int cc = c ^ ((r >> 2) & 7);                                \
            Xl[team][buf][r * 8 + cc] = gx[k2];                               \
            Wl[team][buf][r * 8 + cc] = gv[k2];                               \
        }                                                                     \
    }

    // prologue: stage chunk 0 into buf 0
    {
        float4 gx[4], gv[4];
        STAGE_LOAD(0);
        STAGE_WRITE(0);
    }
    __syncthreads();

    int cur = 0;
    for (int ch = 0; ch < NCHUNK; ++ch) {
        float4 gx[4], gv[4];
        const bool pf = (ch + 1 < NCHUNK);
        if (pf) STAGE_LOAD(ch + 1);     // issue early: hides under compute

        const float4* Xc = Xl[team][cur];
        const float4* Wc = Wl[team][cur];
#pragma unroll
        for (int s = 0; s < 8; ++s) {   // 8 x 4d steps
            float4 wv[4];
#pragma unroll
            for (int n = 0; n < 4; ++n)
                wv[n] = Wc[(tx * 4 + n) * 8 + (s ^ kw)];
#pragma unroll
            for (int m = 0; m < 8; ++m) {
                const int kx = (m < 4) ? kx0 : kx1;
                float4 xv = Xc[(ty * 8 + m) * 8 + (s ^ kx)];
#pragma unroll
                for (int n = 0; n < 4; ++n) {
                    acc[m][n] = fmaf(xv.x, wv[n].x, acc[m][n]);
                    acc[m][n] = fmaf(xv.y, wv[n].y, acc[m][n]);
                    acc[m][n] = fmaf(xv.z, wv[n].z, acc[m][n]);
                    acc[m][n] = fmaf(xv.w, wv[n].w, acc[m][n]);
                }
            }
        }

        if (pf) STAGE_WRITE(cur ^ 1);   // vmcnt wait lands here, not in compute
        __syncthreads();
        cur ^= 1;
    }

    // ---- reduce teams in ascending-D order (determinism vs np) ----
    // lp[tok][exp ^ (tok&31)] : XOR keeps the top-2 scan conflict-free
#pragma unroll
    for (int ph = 0; ph < 4; ++ph) {
        if (team == ph) {
#pragma unroll
            for (int m = 0; m < 8; ++m) {
                const int tok = ty * 8 + m;
#pragma unroll
                for (int n = 0; n < 4; ++n) {
                    const int e = tx * 4 + n;
                    const int idx = tok * 64 + (e ^ (tok & 31));
                    if (ph == 0) lp[idx] = acc[m][n];
                    else         lp[idx] += acc[m][n];
                }
            }
        }
        __syncthreads();
    }

    // ---- top-2 + softmax: one lane per token ----
    if (tid < BLK_TOK) {
        const int t = tid;
        float m1 = -INFINITY, m2 = -INFINITY;
        int i1 = 0, i2 = 0;
        for (int e = 0; e < NEXP; ++e) {
            float v = lp[t * 64 + (e ^ (t & 31))];
            if (v > m1) {              // strict '>' keeps lowest index on ties
                m2 = m1; i2 = i1;
                m1 = v;  i1 = e;
            } else if (v > m2) {
                m2 = v;  i2 = e;
            }
        }
        float e2 = expf(m2 - m1);
        float denom = 1.f + e2;

        const int gt = tok0 + t;
        out[gt * 2 + 0] = 1.f / denom;
        out[gt * 2 + 1] = e2 / denom;
        out[NTOK * 2 + gt * 2 + 0] = (float)i1;
        out[NTOK * 2 + gt * 2 + 1] = (float)i2;
    }
}

extern "C" void kernel_launch(void* const* d_in, const int* in_sizes, int n_in,
                              void* d_out, int out_size, void* d_ws, size_t ws_size,
                              hipStream_t stream) {
    const float* x  = (const float*)d_in[0];   // [4,4096,2048] f32
    const float* gw = (const float*)d_in[1];   // [64,2048] f32
    float* out = (float*)d_out;

    dim3 grid(NTOK / BLK_TOK);   // 256 blocks
    dim3 block(512);             // 4 teams x 128
    moe_gemm_kernel<<<grid, block, 0, stream>>>(x, gw, out);
}

// Round 4
// 175.963 us; speedup vs baseline: 3.8119x; 3.8119x over previous
//
#include <hip/hip_runtime.h>
#include <math.h>

// MoE router: logits[16384,64] = X[16384,2048] @ W^T (fp32), top-2, softmax(2).
// Outputs flat: weights [16384*2] f32, then indices [16384*2] as float.
//
// R1: runtime-indexed acc -> scratch spill (293MB wr).
// R3: register-staged LDS tiles + big unroll -> spill again (2.7GB traffic,
//     kernel ran at memcpy speed of its own spill).
// R4 design: NOTHING staged through VGPRs.
//   - W tile -> LDS via global_load_lds (DMA, 0 registers), double-buffered.
//   - X per-lane global loads (token per lane), 4 tokens/lane.
//   - per lane: 4 tok x 16 exp acc (64 regs, all static). Per d4-step:
//     256 FMA (512 cyc/wave) vs 16 uniform-broadcast ds_read_b128 (192 cyc)
//     vs 4 VMEM -> VALU-bound.
//   - split-D into NS slices for occupancy: grid = 64 token-groups * NS,
//     partials to d_ws, second tiny kernel reduces + top-2 + softmax.
//   - d4 loop DYNAMIC (16 iters, ~300 instr body): no icache blowup, no
//     allocator pressure from giant unroll.

#define NTOK 16384
#define DDIM 2048
#define NEXP 64
#define DC 64                 // d per LDS chunk
#define SLICE_ELTS (NTOK * NEXP)   // floats per ws slice

__device__ static inline void gload_lds16(const float* gsrc, float* ldst) {
    __builtin_amdgcn_global_load_lds(
        (const __attribute__((address_space(1))) void*)gsrc,
        (__attribute__((address_space(3))) void*)ldst, 16, 0, 0);
}

template <int NS>
__global__ __launch_bounds__(256, 2) void moe_partial_kernel(
    const float* __restrict__ x,      // [NTOK, DDIM]
    const float* __restrict__ gw,     // [NEXP, DDIM]
    float* __restrict__ ws)           // [NS][NTOK][NEXP] partials
{
    __shared__ float Wl[2][NEXP * DC];   // 2 x 16 KB

    const int tid  = threadIdx.x;
    const int lane = tid & 63;
    const int eg   = __builtin_amdgcn_readfirstlane(tid >> 6); // expert group 0..3
    const int dsl  = blockIdx.x & (NS - 1);
    const int tg   = blockIdx.x / NS;
    const int T0   = tg * 256;
    const int DSL  = DDIM / NS;          // d per slice
    const int NCH  = DSL / DC;           // chunks per slice
    const int d0   = dsl * DSL;

    // ---- W staging: chunk = [64 exp][64 d] f32, linear in 16B units.
    // unit u = tid + s*256 : e = u>>4, dq = u&15 ; dest byte = u*16.
#define STAGE(ch, buf)                                                        \
    {                                                                         \
        const int dcol = d0 + (ch) * DC;                                      \
        _Pragma("unroll")                                                     \
        for (int s = 0; s < 4; ++s) {                                         \
            const int u = tid + s * 256;                                      \
            gload_lds16(gw + (size_t)(u >> 4) * DDIM + dcol + (u & 15) * 4,   \
                        &Wl[buf][u * 4]);                                     \
        }                                                                     \
    }

    float acc[4][16];
#pragma unroll
    for (int t = 0; t < 4; ++t)
#pragma unroll
        for (int e = 0; e < 16; ++e) acc[t][e] = 0.f;

    const float* xbase = x + (size_t)(T0 + lane) * DDIM + d0;

    STAGE(0, 0);
    __syncthreads();

    int cur = 0;
    for (int ch = 0; ch < NCH; ++ch) {
        if (ch + 1 < NCH) STAGE(ch + 1, cur ^ 1);   // async DMA into other buf

        const float* Wc = &Wl[cur][eg * 16 * DC];   // this wave's 16 experts
        const float* xc = xbase + ch * DC;

        for (int d4 = 0; d4 < DC / 4; ++d4) {       // dynamic: small body
            float4 xv[4];
#pragma unroll
            for (int t = 0; t < 4; ++t)
                xv[t] = *reinterpret_cast<const float4*>(
                    xc + (size_t)t * 64 * DDIM + d4 * 4);
#pragma unroll
            for (int e = 0; e < 16; ++e) {
                // wave-uniform address -> LDS broadcast, conflict-free
                float4 wv = *reinterpret_cast<const float4*>(
                    Wc + e * DC + d4 * 4);
#pragma unroll
                for (int t = 0; t < 4; ++t) {
                    acc[t][e] = fmaf(xv[t].x, wv.x, acc[t][e]);
                    acc[t][e] = fmaf(xv[t].y, wv.y, acc[t][e]);
                    acc[t][e] = fmaf(xv[t].z, wv.z, acc[t][e]);
                    acc[t][e] = fmaf(xv[t].w, wv.w, acc[t][e]);
                }
            }
        }
        __syncthreads();
        cur ^= 1;
    }

    // partials: ws[dsl][tok][exp], float4 stores (exp contiguous)
    float* wsl = ws + (size_t)dsl * SLICE_ELTS;
#pragma unroll
    for (int t = 0; t < 4; ++t) {
        float* row = wsl + (size_t)(T0 + lane + 64 * t) * NEXP + eg * 16;
#pragma unroll
        for (int q = 0; q < 4; ++q) {
            float4 v = make_float4(acc[t][q * 4 + 0], acc[t][q * 4 + 1],
                                   acc[t][q * 4 + 2], acc[t][q * 4 + 3]);
            *reinterpret_cast<float4*>(row + q * 4) = v;
        }
    }
#undef STAGE
}

template <int NS>
__global__ __launch_bounds__(128) void moe_reduce_kernel(
    const float* __restrict__ ws,     // [NS][NTOK][NEXP]
    float* __restrict__ out)          // weights then indices
{
    const int t = blockIdx.x * 128 + threadIdx.x;   // token
    float m1 = -INFINITY, m2 = -INFINITY;
    int i1 = 0, i2 = 0;

    const float* base = ws + (size_t)t * NEXP;
    for (int e4 = 0; e4 < 16; ++e4) {               // dynamic loop
        float4 s = *reinterpret_cast<const float4*>(base + e4 * 4);
#pragma unroll
        for (int sl = 1; sl < NS; ++sl) {           // ascending-D order
            float4 p = *reinterpret_cast<const float4*>(
                base + (size_t)sl * SLICE_ELTS + e4 * 4);
            s.x += p.x; s.y += p.y; s.z += p.z; s.w += p.w;
        }
        float v[4] = {s.x, s.y, s.z, s.w};
#pragma unroll
        for (int q = 0; q < 4; ++q) {
            const int e = e4 * 4 + q;
            if (v[q] > m1) {            // strict '>' = lowest index on ties
                m2 = m1; i2 = i1;
                m1 = v[q]; i1 = e;
            } else if (v[q] > m2) {
                m2 = v[q]; i2 = e;
            }
        }
    }

    float e2 = expf(m2 - m1);
    float denom = 1.f + e2;
    out[t * 2 + 0] = 1.f / denom;
    out[t * 2 + 1] = e2 / denom;
    out[NTOK * 2 + t * 2 + 0] = (float)i1;
    out[NTOK * 2 + t * 2 + 1] = (float)i2;
}

template <int NS>
static void launch_ns(const float* x, const float* gw, float* ws, float* out,
                      hipStream_t stream) {
    moe_partial_kernel<NS><<<dim3(64 * NS), dim3(256), 0, stream>>>(x, gw, ws);
    moe_reduce_kernel<NS><<<dim3(NTOK / 128), dim3(128), 0, stream>>>(ws, out);
}

extern "C" void kernel_launch(void* const* d_in, const int* in_sizes, int n_in,
                              void* d_out, int out_size, void* d_ws, size_t ws_size,
                              hipStream_t stream) {
    const float* x  = (const float*)d_in[0];   // [4,4096,2048] f32
    const float* gw = (const float*)d_in[1];   // [64,2048] f32
    float* out = (float*)d_out;
    float* ws  = (float*)d_ws;

    const size_t per_slice = (size_t)SLICE_ELTS * sizeof(float);  // 4 MiB
    if      (ws_size >= 8 * per_slice) launch_ns<8>(x, gw, ws, out, stream);
    else if (ws_size >= 4 * per_slice) launch_ns<4>(x, gw, ws, out, stream);
    else if (ws_size >= 2 * per_slice) launch_ns<2>(x, gw, ws, out, stream);
    else                               launch_ns<1>(x, gw, ws, out, stream);
}